// Round 5
// baseline (162.363 us; speedup 1.0000x reference)
//
#include <hip/hip_runtime.h>
#include <math.h>

// ---------------------------------------------------------------------------
// GraphMultisetTransformer forward, MI355X round 5:
//   - projections read A-fragments DIRECTLY from global x/ox (no LDS staging,
//     no staging barriers) -> global loads in flight across the whole phase
//   - 2 barriers per block (was 6); LDS 64KB (Kl/P 32K + Vt 32K), 2 blocks/CU
//   - wd folded into chunk launch (blocks 0..23); 3 launches total
// ---------------------------------------------------------------------------

typedef __bf16 bf16x8 __attribute__((ext_vector_type(8)));
typedef float  f32x4  __attribute__((ext_vector_type(4)));

namespace {
constexpr int kB   = 16;
constexpr int kN   = 4096;
constexpr int kC   = 256;
constexpr int kEV  = 64;
constexpr int kH   = 8;
constexpr int kDH  = 32;
constexpr int kNQ  = 30;
constexpr int kCHUNK = 64;
constexpr int kNCH = kN / kCHUNK;   // 64
constexpr float kScale = 0.625f;    // 1/(16*0.1)
}

__device__ __forceinline__ unsigned short f32_to_bf16(float f) {
  unsigned int u = __float_as_uint(f);
  unsigned int r = (u + 0x7FFFu + ((u >> 16) & 1u)) >> 16;
  return (unsigned short)r;
}
__device__ __forceinline__ f32x4 splat4(float v) {
  f32x4 r; r[0] = v; r[1] = v; r[2] = v; r[3] = v; return r;
}

// ---------------------------------------------------------------------------
// prep: blocks [0,192) convert 6 W matrices f32->bf16; [192,704) Q projection
// ---------------------------------------------------------------------------
__global__ __launch_bounds__(256) void prep_kernel(
    const float* __restrict__ ev,
    const float* __restrict__ WqG, const float* __restrict__ WqD,
    const float* __restrict__ WqL,
    const float* __restrict__ WkG, const float* __restrict__ WkD,
    const float* __restrict__ WkL,
    const float* __restrict__ WvG, const float* __restrict__ WvD,
    const float* __restrict__ WvL,
    unsigned short* __restrict__ Wb,
    float* __restrict__ Qw, unsigned short* __restrict__ Qb)
{
  const int bid = blockIdx.x, tid = threadIdx.x;
  __shared__ float e[kEV];
  if (bid < 192) {
    const int mat = bid >> 5;
    const float* src = (mat == 0) ? WkG : (mat == 1) ? WkD : (mat == 2) ? WkL
                     : (mat == 3) ? WvG : (mat == 4) ? WvD : WvL;
    const int i0 = (((bid & 31) << 8) + tid) * 8;
    const float4* s4 = (const float4*)(src + i0);
    float4 a = s4[0], b = s4[1];
    uint4 pack = make_uint4(
        (unsigned int)f32_to_bf16(a.x) | ((unsigned int)f32_to_bf16(a.y) << 16),
        (unsigned int)f32_to_bf16(a.z) | ((unsigned int)f32_to_bf16(a.w) << 16),
        (unsigned int)f32_to_bf16(b.x) | ((unsigned int)f32_to_bf16(b.y) << 16),
        (unsigned int)f32_to_bf16(b.z) | ((unsigned int)f32_to_bf16(b.w) << 16));
    *(uint4*)(Wb + (size_t)mat * 65536 + i0) = pack;
  } else {
    const int idx = bid - 192;
    const int b = idx >> 5, qq = idx & 31;
    if (qq >= kNQ) { Qb[((size_t)(b * 32 + qq)) * kC + tid] = 0; return; }
    if (tid < kEV) e[tid] = ev[((size_t)(b * kNQ + qq)) * kEV + tid];
    __syncthreads();
    const float* W = (qq < 10) ? WqG : (qq < 20) ? WqD : WqL;
    const float4* wr = (const float4*)(W + (size_t)tid * kEV);
    const float4* er = (const float4*)e;
    float s = 0.0f;
#pragma unroll
    for (int j = 0; j < kEV / 4; ++j) {
      float4 w = wr[j], v = er[j];
      s = fmaf(v.x, w.x, s); s = fmaf(v.y, w.y, s);
      s = fmaf(v.z, w.z, s); s = fmaf(v.w, w.w, s);
    }
    Qw[((size_t)(b * kNQ + qq)) * kC + tid] = s;
    Qb[((size_t)(b * 32 + qq)) * kC + tid] = f32_to_bf16(s * kScale);
  }
}

// ---------------------------------------------------------------------------
// Projection MFMA core (A-frags DIRECT from global f32 rows) + separate store
// ---------------------------------------------------------------------------
struct ProjAcc { f32x4 acc[4][2]; f32x4 accX[2]; };

template <bool HASB>
__device__ __forceinline__ void proj_mfma_g(
    const float* __restrict__ X,          // 64 rows x 256 f32, row-major
    const unsigned short* __restrict__ W0, const unsigned short* __restrict__ W1,
    const float* __restrict__ bias0, const float* __restrict__ bias1,
    int rsplit, bool two, int wcol0, int lane, ProjAcc& P)
{
  const int lg = lane >> 4, lr = lane & 15;
  const bool strad = two && (rsplit & 15);
  const int ms = rsplit >> 4;

#pragma unroll
  for (int n = 0; n < 2; ++n) {
    float b0v = 0.0f, b1v = 0.0f;
    if constexpr (HASB) {
      b0v = bias0[wcol0 + n * 16 + lr];
      b1v = two ? bias1[wcol0 + n * 16 + lr] : b0v;
    }
#pragma unroll
    for (int m = 0; m < 4; ++m)
      P.acc[m][n] = splat4((m * 16 < rsplit) ? b0v : b1v);
    P.accX[n] = splat4(b1v);
  }

#pragma unroll
  for (int kt = 0; kt < 8; ++kt) {
    bf16x8 a[4];
#pragma unroll
    for (int m = 0; m < 4; ++m) {
      const float4* p = (const float4*)(X + (size_t)(m * 16 + lr) * kC + kt * 32 + lg * 8);
      float4 v0 = p[0], v1 = p[1];
      bf16x8 t;
      t[0] = (__bf16)v0.x; t[1] = (__bf16)v0.y; t[2] = (__bf16)v0.z; t[3] = (__bf16)v0.w;
      t[4] = (__bf16)v1.x; t[5] = (__bf16)v1.y; t[6] = (__bf16)v1.z; t[7] = (__bf16)v1.w;
      a[m] = t;
    }
    bf16x8 ams = a[0];
#pragma unroll
    for (int m = 1; m < 4; ++m) if (m == ms) ams = a[m];

    const int k0 = kt * 32 + lg * 8;
#pragma unroll
    for (int n = 0; n < 2; ++n) {
      const int ct = wcol0 + n * 16 + lr;
      bf16x8 b0 = *reinterpret_cast<const bf16x8*>(W0 + (size_t)ct * kC + k0);
      if (!two) {
#pragma unroll
        for (int m = 0; m < 4; ++m)
          P.acc[m][n] = __builtin_amdgcn_mfma_f32_16x16x32_bf16(a[m], b0, P.acc[m][n], 0, 0, 0);
      } else {
        bf16x8 b1 = *reinterpret_cast<const bf16x8*>(W1 + (size_t)ct * kC + k0);
#pragma unroll
        for (int m = 0; m < 4; ++m) {
          bf16x8 bs = (m * 16 < rsplit) ? b0 : b1;
          P.acc[m][n] = __builtin_amdgcn_mfma_f32_16x16x32_bf16(a[m], bs, P.acc[m][n], 0, 0, 0);
        }
        if (strad)
          P.accX[n] = __builtin_amdgcn_mfma_f32_16x16x32_bf16(ams, b1, P.accX[n], 0, 0, 0);
      }
    }
  }
}

// VT=false: dst[row][col] swizzled (K layout); VT=true: dst[col][key] swizzled
template <bool VT>
__device__ __forceinline__ void proj_store(
    unsigned short* dst, const ProjAcc& P,
    int rsplit, bool two, int wcol0, int lane)
{
  const int lg = lane >> 4, lr = lane & 15;
  const bool strad = two && (rsplit & 15);
  const int ms = rsplit >> 4;
#pragma unroll
  for (int m = 0; m < 4; ++m) {
#pragma unroll
    for (int n = 0; n < 2; ++n) {
      const int col = wcol0 + n * 16 + lr;
      if constexpr (VT) {
        unsigned short us[4];
#pragma unroll
        for (int j = 0; j < 4; ++j) {
          const int row = m * 16 + lg * 4 + j;
          float v = P.acc[m][n][j];
          if (strad && m == ms && row >= rsplit) v = P.accX[n][j];
          us[j] = f32_to_bf16(v);
        }
        const int row0 = m * 16 + lg * 4;
        const int ck = ((row0 >> 3) ^ (col & 7));
        uint2 pk = make_uint2((unsigned int)us[0] | ((unsigned int)us[1] << 16),
                              (unsigned int)us[2] | ((unsigned int)us[3] << 16));
        *(uint2*)(dst + col * kCHUNK + ck * 8 + (row0 & 7)) = pk;
      } else {
#pragma unroll
        for (int j = 0; j < 4; ++j) {
          const int row = m * 16 + lg * 4 + j;
          float v = P.acc[m][n][j];
          if (strad && m == ms && row >= rsplit) v = P.accX[n][j];
          dst[row * kC + (col ^ ((row & 7) << 3))] = f32_to_bf16(v);
        }
      }
    }
  }
}

// ---------------------------------------------------------------------------
// Chunk kernel (+wd): blocks [0,24) compute wd partials; blocks [24,...) are
// compacted live chunks. 512 threads, 64KB LDS -> 2 blocks/CU.
// Phases: projK(direct) -> Kl; projV(direct) -> Vt; B1; QK^T; B2; P -> Kl
// alias; PV; partial-sum stores.
// ---------------------------------------------------------------------------
__global__ __launch_bounds__(512, 4) void chunk_kernel(
    const float* __restrict__ x, const float* __restrict__ ox,
    const int* __restrict__ numv,
    const unsigned short* __restrict__ Wb,
    const float* __restrict__ bvG, const float* __restrict__ bvD,
    const float* __restrict__ bvL,
    const unsigned short* __restrict__ Qb,
    const float* __restrict__ Qw,
    float* __restrict__ Pl, float* __restrict__ Po, float* __restrict__ wdp)
{
  __shared__ unsigned short Kl[kCHUNK * kC];   // K, then P (wave-private 4KB)
  __shared__ unsigned short Vt[kC * kCHUNK];   // V transposed [c][key]

  const int tid = threadIdx.x;

  // ---- wd partial blocks ----
  if (blockIdx.x < 24) {
    const int g = blockIdx.x >> 3;
    const int h = blockIdx.x & 7;
    const int lo = g * 10;
    float* sred = (float*)Kl;
    float local = 0.0f;
    for (int b = 0; b < kB; ++b) {
      float v = 0.0f;
      if (tid < 100) {
        int i = tid / 10, j = tid % 10;
        const float* qi = Qw + ((size_t)(b * kNQ + lo + i)) * kC + h * kDH;
        const float* qj = Qw + ((size_t)(b * kNQ + lo + j)) * kC + h * kDH;
        float corr = 0.0f;
#pragma unroll
        for (int k = 0; k < kDH; ++k) corr = fmaf(qi[k], qj[k], corr);
        float diff = corr - (i == j ? 1.0f : 0.0f);
        v = diff * diff;
      }
      sred[tid] = v;
      __syncthreads();
      for (int s2 = 256; s2 > 0; s2 >>= 1) {
        if (tid < s2) sred[tid] += sred[tid + s2];
        __syncthreads();
      }
      if (tid == 0) local += sqrtf(sred[0]);
      __syncthreads();
    }
    if (tid == 0) wdp[blockIdx.x] = local * (1.0f / 16.0f);
    return;
  }

  // ---- live-chunk compaction ----
  int nv[17];
#pragma unroll
  for (int i = 0; i < 17; ++i) nv[i] = numv[i];
  int t = blockIdx.x - 24, b = 0, ch = -1;
#pragma unroll
  for (int bb = 0; bb < kB; ++bb) {
    const int lc = (3 * (nv[bb + 1] - nv[bb]) + 63) >> 6;
    if (ch < 0) { if (t < lc) { b = bb; ch = t; } else t -= lc; }
  }
  if (ch < 0) return;

  const int n0 = ch * kCHUNK;
  const int d = nv[b + 1] - nv[b];
  const int limit = 3 * d;
  const int nvalid = min(kCHUNK, limit - n0);

  const int lane = tid & 63, wv = tid >> 6;
  const int lg = lane >> 4, lr = lane & 15;
  const int wcol0 = wv * 32;

  // group structure: at most one boundary inside a 64-row chunk (d >= 64)
  const int g0 = (n0 >= 2 * d) ? 2 : (n0 >= d) ? 1 : 0;
  const int n63 = n0 + 63;
  const int g1 = (n63 >= 2 * d) ? 2 : (n63 >= d) ? 1 : 0;
  const bool two = (g1 != g0);
  const int rsplit = two ? ((g1 == 1 ? d : 2 * d) - n0) : kCHUNK;

  const unsigned short* WkA = Wb + (size_t)g0 * 65536;
  const unsigned short* WkB = Wb + (size_t)g1 * 65536;
  const unsigned short* WvA = Wb + (size_t)(3 + g0) * 65536;
  const unsigned short* WvB = Wb + (size_t)(3 + g1) * 65536;
  const float* bvA = (g0 == 0) ? bvG : (g0 == 1) ? bvD : bvL;
  const float* bvB = (g1 == 0) ? bvG : (g1 == 1) ? bvD : bvL;

  // ---- K projection (A-frags direct from x) ----
  {
    ProjAcc PK;
    proj_mfma_g<false>(x + ((size_t)b * kN + n0) * kC, WkA, WkB,
                       nullptr, nullptr, rsplit, two, wcol0, lane, PK);
    proj_store<false>(Kl, PK, rsplit, two, wcol0, lane);
  }

  // ---- V projection (A-frags direct from ox) ----
  {
    ProjAcc PV;
    proj_mfma_g<true>(ox + ((size_t)b * kN + n0) * kC, WvA, WvB,
                      bvA, bvB, rsplit, two, wcol0, lane, PV);
    proj_store<true>(Vt, PV, rsplit, two, wcol0, lane);
  }
  __syncthreads();                                        // B1: Kl & Vt ready

  // ---- attention: wave = head h ----
  const int h = wv;
  const unsigned short* qrow = Qb + (size_t)b * 32 * kC;
  bf16x8 aq0 = *reinterpret_cast<const bf16x8*>(qrow + lr * kC + h * kDH + lg * 8);
  bf16x8 aq1 = *reinterpret_cast<const bf16x8*>(qrow + (16 + lr) * kC + h * kDH + lg * 8);

  f32x4 s[2][4];
#pragma unroll
  for (int m = 0; m < 2; ++m)
#pragma unroll
    for (int n = 0; n < 4; ++n) s[m][n] = splat4(0.0f);

#pragma unroll
  for (int n = 0; n < 4; ++n) {
    const int row = n * 16 + lr;
    const int c16 = (h * 4 + lg) ^ (row & 7);
    bf16x8 bk = *reinterpret_cast<const bf16x8*>(Kl + row * kC + c16 * 8);
    s[0][n] = __builtin_amdgcn_mfma_f32_16x16x32_bf16(aq0, bk, s[0][n], 0, 0, 0);
    s[1][n] = __builtin_amdgcn_mfma_f32_16x16x32_bf16(aq1, bk, s[1][n], 0, 0, 0);
  }
  __syncthreads();                                        // B2: Kl reads done

  unsigned short* Pw = Kl + wv * 2048;     // wave-private P [32 q][64 key]
  f32x4 lsum[2];
  lsum[0] = splat4(0.0f); lsum[1] = splat4(0.0f);

#pragma unroll
  for (int m = 0; m < 2; ++m) {
#pragma unroll
    for (int n = 0; n < 4; ++n) {
      const int key = n * 16 + lr;
      const bool kok = key < nvalid;
      f32x4 p;
#pragma unroll
      for (int j = 0; j < 4; ++j) p[j] = kok ? __expf(s[m][n][j]) : 0.0f;
      lsum[m] += p;
#pragma unroll
      for (int j = 0; j < 4; ++j) {
        const int q = m * 16 + lg * 4 + j;
        const int ck = (key >> 3) ^ (q & 7);
        Pw[q * kCHUNK + ck * 8 + (key & 7)] = f32_to_bf16(p[j]);
      }
    }
  }

  // l: reduce over the 16 key-lanes
#pragma unroll
  for (int msk = 1; msk < 16; msk <<= 1) {
#pragma unroll
    for (int m = 0; m < 2; ++m)
#pragma unroll
      for (int j = 0; j < 4; ++j)
        lsum[m][j] += __shfl_xor(lsum[m][j], msk, 16);
  }
  const int plbase = (b * kNCH + ch) * kNQ * kH;
  if (lr == 0) {
#pragma unroll
    for (int m = 0; m < 2; ++m)
#pragma unroll
      for (int j = 0; j < 4; ++j) {
        const int q = m * 16 + lg * 4 + j;
        if (q < kNQ) Pl[plbase + q * kH + h] = lsum[m][j];
      }
  }

  // PV: O[q][dh] = sum_k P[q][k] * V[k][dh]   (reads own-wave P: no barrier)
  f32x4 o[2][2];
#pragma unroll
  for (int m = 0; m < 2; ++m)
#pragma unroll
    for (int n = 0; n < 2; ++n) o[m][n] = splat4(0.0f);

#pragma unroll
  for (int ks = 0; ks < 2; ++ks) {
    const int ckp = (ks * 4 + lg) ^ (lr & 7);
    bf16x8 ap0 = *reinterpret_cast<const bf16x8*>(Pw + lr * kCHUNK + ckp * 8);
    bf16x8 ap1 = *reinterpret_cast<const bf16x8*>(Pw + (16 + lr) * kCHUNK + ckp * 8);
#pragma unroll
    for (int n = 0; n < 2; ++n) {
      const int c = h * kDH + n * 16 + lr;
      const int ckv = (ks * 4 + lg) ^ (c & 7);
      bf16x8 bv = *reinterpret_cast<const bf16x8*>(Vt + c * kCHUNK + ckv * 8);
      o[0][n] = __builtin_amdgcn_mfma_f32_16x16x32_bf16(ap0, bv, o[0][n], 0, 0, 0);
      o[1][n] = __builtin_amdgcn_mfma_f32_16x16x32_bf16(ap1, bv, o[1][n], 0, 0, 0);
    }
  }

#pragma unroll
  for (int m = 0; m < 2; ++m)
#pragma unroll
    for (int n = 0; n < 2; ++n)
#pragma unroll
      for (int j = 0; j < 4; ++j) {
        const int q = m * 16 + lg * 4 + j;
        if (q < kNQ)
          Po[((size_t)(plbase + q * kH + h)) * kDH + n * 16 + lr] = o[m][n][j];
      }
}

// ---------------------------------------------------------------------------
// Combine: block [0,480) = (b,q) partial-sum + epilogue; block 480 = wd total
// ---------------------------------------------------------------------------
__global__ __launch_bounds__(256) void combine_kernel(
    const float* __restrict__ Pl, const float* __restrict__ Po,
    const int* __restrict__ numv,
    const float* __restrict__ Wo, const float* __restrict__ bo,
    const float* __restrict__ wdp,
    float* __restrict__ out)
{
  const int bq = blockIdx.x;
  const int tid = threadIdx.x;

  if (bq == kB * kNQ) {     // wd finalize
    float v = (tid < 24) ? wdp[tid] : 0.0f;
#pragma unroll
    for (int off = 32; off > 0; off >>= 1) v += __shfl_down(v, off);
    if (tid == 0) out[(size_t)kB * kNQ * kC] = v;
    return;
  }

  const int b = bq / kNQ, q = bq % kNQ;
  const int h = tid >> 5, kk = tid & 31;

  const int d = numv[b + 1] - numv[b];
  const int ncv = min(kNCH, (3 * d + kCHUNK - 1) >> 6);

  float l = 0.0f, oacc = 0.0f;
#pragma unroll 4
  for (int ch = 0; ch < ncv; ++ch) {
    const int idx = (b * kNCH + ch) * kNQ * kH + q * kH + h;
    l += Pl[idx];
    oacc += Po[(size_t)idx * kDH + kk];
  }
  const float attn = oacc / l;

  __shared__ float row[kC];
  row[tid] = attn;
  __syncthreads();

  const float4* wr = (const float4*)(Wo + (size_t)tid * kC);
  const float4* rr = (const float4*)row;
  float s = 0.0f;
#pragma unroll
  for (int j = 0; j < kC / 4; ++j) {
    float4 w = wr[j], v = rr[j];
    s = fmaf(v.x, w.x, s); s = fmaf(v.y, w.y, s);
    s = fmaf(v.z, w.z, s); s = fmaf(v.w, w.w, s);
  }
  s += bo[tid];
  const float y = attn + fmaxf(s, 0.0f);

  float v = y * y;
#pragma unroll
  for (int off = 32; off > 0; off >>= 1) v += __shfl_down(v, off);
  __shared__ float red[4];
  if ((tid & 63) == 0) red[tid >> 6] = v;
  __syncthreads();
  const float tot = red[0] + red[1] + red[2] + red[3];
  const float nrm = fmaxf(sqrtf(tot), 1e-12f);
  out[(size_t)bq * kC + tid] = y / nrm;
}

// ---------------------------------------------------------------------------
extern "C" void kernel_launch(void* const* d_in, const int* in_sizes, int n_in,
                              void* d_out, int out_size, void* d_ws, size_t ws_size,
                              hipStream_t stream) {
  const float* x    = (const float*)d_in[0];
  const float* ox   = (const float*)d_in[1];
  const float* ev   = (const float*)d_in[2];
  // d_in[3] = mask_cross: recomputed from numv, unused
  const int*   numv = (const int*)d_in[4];
  const float* WqG  = (const float*)d_in[5];
  const float* WqD  = (const float*)d_in[6];
  const float* WqL  = (const float*)d_in[7];
  const float* WkG  = (const float*)d_in[8];
  const float* WkD  = (const float*)d_in[9];
  const float* WkL  = (const float*)d_in[10];
  const float* WvG  = (const float*)d_in[11];
  const float* bvG  = (const float*)d_in[12];
  const float* WvD  = (const float*)d_in[13];
  const float* bvD  = (const float*)d_in[14];
  const float* WvL  = (const float*)d_in[15];
  const float* bvL  = (const float*)d_in[16];
  const float* Wo   = (const float*)d_in[17];
  const float* bo   = (const float*)d_in[18];

  float* out = (float*)d_out;
  char*  ws  = (char*)d_ws;

  // workspace layout (bytes)
  float* Qw = (float*)ws;                                        // 491,520
  unsigned short* Qb = (unsigned short*)(ws + 491520);           // 262,144
  unsigned short* Wb = (unsigned short*)(ws + 491520 + 262144);  // 786,432
  float* Pl  = (float*)(ws + 1540096);                           // 983,040
  float* Po  = (float*)(ws + 1540096 + 983040);                  // 31,457,280
  float* wdp = (float*)(ws + 1540096 + 983040 + 31457280);       // 96

  prep_kernel<<<704, 256, 0, stream>>>(ev, WqG, WqD, WqL,
                                       WkG, WkD, WkL, WvG, WvD, WvL,
                                       Wb, Qw, Qb);
  chunk_kernel<<<24 + kB * kNCH, 512, 0, stream>>>(
      x, ox, numv, Wb, bvG, bvD, bvL, Qb, Qw, Pl, Po, wdp);
  combine_kernel<<<kB * kNQ + 1, 256, 0, stream>>>(Pl, Po, numv, Wo, bo, wdp, out);
}